// Round 11
// baseline (717.395 us; speedup 1.0000x reference)
//
#include <hip/hip_runtime.h>
#include <float.h>
#include <math.h>

#define N_NODES 50000
#define N_EDGES 1600000
#define NB      64
#define HID     128
#define TOT     (N_EDGES + N_NODES)
#define PARTS   16
#define SCAN_NB 196   // ceil(50000/256)
#define NPART   8
#define PSIZE   6250  // 50000/8
#define EPB     1024  // edges per block in partitioned kernels
#define GM_ROWS 64    // rows per block in MFMA gemm

typedef __attribute__((ext_vector_type(8))) short short8;
typedef __attribute__((ext_vector_type(4))) float f32x4;
typedef __attribute__((ext_vector_type(2))) float f32x2;

__device__ __forceinline__ float gelu_f(float x){
    return 0.5f * x * (1.0f + erff(x * 0.70710678118654752440f));
}

__device__ __forceinline__ float asf(unsigned int u){
    union { unsigned int i; float f; } c; c.i = u; return c.f;
}
__device__ __forceinline__ float bf2f(unsigned short u){
    return asf(((unsigned int)u) << 16);
}
__device__ __forceinline__ unsigned short f2bf(float x){
    union { float f; unsigned int i; } c; c.f = x;
    unsigned int r = c.i + 0x7fffu + ((c.i >> 16) & 1u);
    return (unsigned short)(r >> 16);
}
__device__ __forceinline__ uint2 pack4(float a, float b, float cc, float d){
    uint2 r;
    r.x = (unsigned int)f2bf(a) | ((unsigned int)f2bf(b) << 16);
    r.y = (unsigned int)f2bf(cc) | ((unsigned int)f2bf(d) << 16);
    return r;
}
__device__ __forceinline__ unsigned short sel_head(uint2 v, int hd){
    return (hd & 2) ? ((hd & 1) ? (unsigned short)(v.y >> 16) : (unsigned short)(v.y & 0xffff))
                    : ((hd & 1) ? (unsigned short)(v.x >> 16) : (unsigned short)(v.x & 0xffff));
}

// block of 128 threads (2 waves) sum-reduce; red must be float[>=2] shared
__device__ __forceinline__ float blk_sum128(float v, float* red){
    #pragma unroll
    for (int m = 32; m > 0; m >>= 1) v += __shfl_xor(v, m, 64);
    __syncthreads();
    if ((threadIdx.x & 63) == 0) red[threadIdx.x >> 6] = v;
    __syncthreads();
    float r = red[0] + red[1];
    __syncthreads();
    return r;
}

// inclusive scan across 256 threads; wsum must be int[4] shared
__device__ __forceinline__ int blk_scan256(int v, int* wsum){
    int t = threadIdx.x, lane = t & 63, w = t >> 6;
    int x = v;
    #pragma unroll
    for (int off = 1; off < 64; off <<= 1){
        int y = __shfl_up(x, off, 64);
        if (lane >= off) x += y;
    }
    if (lane == 63) wsum[w] = x;
    __syncthreads();
    if (t == 0){
        int s = 0;
        #pragma unroll
        for (int i = 0; i < 4; i++){ int tmp = wsum[i]; wsum[i] = s; s += tmp; }
    }
    __syncthreads();
    return x + wsum[w];
}

// ---------------- encoder: h = gelu(LN(x@enc_w+enc_b)) ----------------
__global__ void enc_kernel(const float* __restrict__ x, const float* __restrict__ enc_w,
                           const float* __restrict__ enc_b, const float* __restrict__ enc_g,
                           const float* __restrict__ enc_beta, float* __restrict__ h)
{
    __shared__ float xs[12];
    __shared__ float red[2];
    int n = blockIdx.x, t = threadIdx.x;
    if (t < 12) xs[t] = x[n * 12 + t];
    __syncthreads();
    float acc = enc_b[t];
    #pragma unroll
    for (int k = 0; k < 12; k++) acc += xs[k] * enc_w[k * HID + t];
    float mean = blk_sum128(acc, red) * (1.0f / HID);
    float d = acc - mean;
    float var = blk_sum128(d * d, red) * (1.0f / HID);
    float y = d * rsqrtf(var + 1e-5f) * enc_g[t] + enc_beta[t];
    h[(size_t)n * HID + t] = gelu_f(y);
}

// ---------------- CSR build (dst-partitioned for XCD write locality) ----------------
__global__ void count_kernel(const int* __restrict__ ei, int* __restrict__ row_count){
    int part = blockIdx.x & (NPART - 1);
    int slice = blockIdx.x >> 3;
    int lo = part * PSIZE, hi = lo + PSIZE;
    int base = slice * EPB;
    int iend = min(base + EPB, N_EDGES);
    for (int i = base + threadIdx.x; i < iend; i += 256){
        int d = ei[N_EDGES + i];
        if (d >= lo && d < hi) atomicAdd(&row_count[d], 1);
    }
}

// per-block totals of (count+1)
__global__ void scan1_kernel(const int* __restrict__ row_count, int* __restrict__ bsum){
    __shared__ int ws[4];
    int i = blockIdx.x * 256 + threadIdx.x;
    int v = (i < N_NODES) ? (row_count[i] + 1) : 0;
    int x = v;
    #pragma unroll
    for (int m = 32; m > 0; m >>= 1) x += __shfl_xor(x, m, 64);
    if ((threadIdx.x & 63) == 0) ws[threadIdx.x >> 6] = x;
    __syncthreads();
    if (threadIdx.x == 0) bsum[blockIdx.x] = ws[0] + ws[1] + ws[2] + ws[3];
}

// exclusive scan of the 196 block sums (single small block)
__global__ void scan2_kernel(int* __restrict__ bsum){
    __shared__ int ws[4];
    int t = threadIdx.x;
    int v = (t < SCAN_NB) ? bsum[t] : 0;
    int incl = blk_scan256(v, ws);
    if (t < SCAN_NB) bsum[t] = incl - v;   // exclusive
}

// per-block rescan + offset -> row_ptr and cursor
__global__ void scan3_kernel(const int* __restrict__ row_count, const int* __restrict__ bsum,
                             int* __restrict__ row_ptr, int* __restrict__ cursor){
    __shared__ int ws[4];
    int i = blockIdx.x * 256 + threadIdx.x;
    int v = (i < N_NODES) ? (row_count[i] + 1) : 0;
    int incl = blk_scan256(v, ws) + bsum[blockIdx.x];
    if (i < N_NODES){
        row_ptr[i + 1] = incl;
        cursor[i] = incl - v;
    }
    if (i == 0) row_ptr[0] = 0;
}

// partitioned scatter: single int2 {src,eid} write per position, XCD-localized.
// Also zeroes the alp records at self-loop positions (so selfae can sum branch-free).
__global__ void scatter_kernel(const int* __restrict__ ei, int* __restrict__ cursor,
                               int2* __restrict__ csr_se, int* __restrict__ self_pos,
                               uint2* __restrict__ alp0, uint2* __restrict__ alp1,
                               uint2* __restrict__ alp2){
    int part = blockIdx.x & (NPART - 1);
    int slice = blockIdx.x >> 3;
    int lo = part * PSIZE, hi = lo + PSIZE;
    int base = slice * EPB;
    int iend = min(base + EPB, TOT);
    for (int i = base + threadIdx.x; i < iend; i += 256){
        int d = (i < N_EDGES) ? ei[N_EDGES + i] : (i - N_EDGES);
        if (d < lo || d >= hi) continue;
        int s = (i < N_EDGES) ? ei[i] : d;
        int pos = atomicAdd(&cursor[d], 1);
        csr_se[pos] = make_int2(s, i);
        if (i >= N_EDGES){
            self_pos[d] = pos;
            uint2 z = make_uint2(0u, 0u);
            alp0[pos] = z; alp1[pos] = z; alp2[pos] = z;
        }
    }
}

// ---------------- We3[l][k][h] = sum_c gat_edge_w[l][k][h*32+c]*att_edge[l][h*32+c] ----------------
__global__ void we3_kernel(const float* __restrict__ gat_edge_w, const float* __restrict__ att_edge,
                           float* __restrict__ We3)
{
    int t = threadIdx.x;          // 256 threads
    int k = t >> 2, hd = t & 3;
    for (int l = 0; l < 3; l++){
        float s = 0.f;
        #pragma unroll
        for (int c = 0; c < 32; c++)
            s += gat_edge_w[(size_t)l * 64 * HID + k * HID + hd * 32 + c]
               * att_edge[l * HID + hd * 32 + c];
        We3[(l * 64 + k) * 4 + hd] = s;
    }
}

// ---------------- per-position a_e for ALL 3 layers, CSR ORDER ----------------
// pk-paired sigmoid-form gelu: gelu_tanh(x) = x * rcp(1 + exp2(-2.3021182*x*(1+0.044715x^2)))
__global__ void ae_pos_kernel(const int2* __restrict__ csr_se, const float4* __restrict__ edge_attr,
                              const float* __restrict__ ee_w, const float* __restrict__ ee_b,
                              const float* __restrict__ We3,
                              uint2* __restrict__ alp0, uint2* __restrict__ alp1,
                              uint2* __restrict__ alp2)
{
    int p = blockIdx.x * 256 + threadIdx.x;
    if (p >= TOT) return;
    int2 se = csr_se[p];
    if (se.y >= N_EDGES) return;             // self-loop positions stay zero (filled by selfae)
    float4 ea = edge_attr[se.y];
    const f32x2* w0 = (const f32x2*)(ee_w);
    const f32x2* w1 = (const f32x2*)(ee_w + 64);
    const f32x2* w2 = (const f32x2*)(ee_w + 128);
    const f32x2* w3 = (const f32x2*)(ee_w + 192);
    const f32x2* bb = (const f32x2*)(ee_b);
    const f32x2* Wv = (const f32x2*)(We3);   // Wv[(l*64+k)*2 + {0,1}]

    f32x2 eax = {ea.x, ea.x}, eay = {ea.y, ea.y}, eaz = {ea.z, ea.z}, eaw = {ea.w, ea.w};
    const f32x2 one2 = {1.0f, 1.0f};
    const f32x2 c044 = {0.044715f, 0.044715f};
    const f32x2 kneg = {-2.3021182f, -2.3021182f};   // -2 * 0.7978845608 * log2(e)

    f32x2 acc[6];
    #pragma unroll
    for (int i = 0; i < 6; i++) acc[i] = (f32x2){0.f, 0.f};

    #pragma unroll 4
    for (int m = 0; m < 32; m++){
        f32x2 u = bb[m];
        u = __builtin_elementwise_fma(eax, w0[m], u);
        u = __builtin_elementwise_fma(eay, w1[m], u);
        u = __builtin_elementwise_fma(eaz, w2[m], u);
        u = __builtin_elementwise_fma(eaw, w3[m], u);
        f32x2 a = u * u;
        f32x2 b = __builtin_elementwise_fma(c044, a, one2);
        f32x2 c = u * kneg;
        f32x2 z = c * b;
        f32x2 e = { __builtin_amdgcn_exp2f(z.x), __builtin_amdgcn_exp2f(z.y) };
        f32x2 d = e + one2;
        f32x2 r = { __builtin_amdgcn_rcpf(d.x), __builtin_amdgcn_rcpf(d.y) };
        f32x2 g = u * r;
        f32x2 gx = {g.x, g.x}, gy = {g.y, g.y};
        #pragma unroll
        for (int l = 0; l < 3; l++){
            int base = (l * 64 + 2 * m) * 2;
            acc[l*2+0] = __builtin_elementwise_fma(gx, Wv[base + 0], acc[l*2+0]);
            acc[l*2+1] = __builtin_elementwise_fma(gx, Wv[base + 1], acc[l*2+1]);
            acc[l*2+0] = __builtin_elementwise_fma(gy, Wv[base + 2], acc[l*2+0]);
            acc[l*2+1] = __builtin_elementwise_fma(gy, Wv[base + 3], acc[l*2+1]);
        }
    }
    alp0[p] = pack4(acc[0].x, acc[0].y, acc[1].x, acc[1].y);
    alp1[p] = pack4(acc[2].x, acc[2].y, acc[3].x, acc[3].y);
    alp2[p] = pack4(acc[4].x, acc[4].y, acc[5].x, acc[5].y);
}

// ---------------- self-loop a_e = mean of row's real-edge a_e (self slot pre-zeroed) ----------------
__global__ __launch_bounds__(64) void selfae_kernel(
        const int* __restrict__ row_ptr, const int* __restrict__ self_pos,
        uint2* __restrict__ alp0, uint2* __restrict__ alp1, uint2* __restrict__ alp2)
{
    int n = blockIdx.x, t = threadIdx.x;   // 64 threads = 1 wave
    int start = row_ptr[n], end = row_ptr[n + 1];
    int sp = self_pos[n];
    float v[12];
    #pragma unroll
    for (int i = 0; i < 12; i++) v[i] = 0.f;
    for (int p = start + t; p < end; p += 64){
        uint2 q0 = alp0[p], q1 = alp1[p], q2 = alp2[p];
        v[0] += asf(q0.x << 16); v[1] += asf(q0.x & 0xffff0000u);
        v[2] += asf(q0.y << 16); v[3] += asf(q0.y & 0xffff0000u);
        v[4] += asf(q1.x << 16); v[5] += asf(q1.x & 0xffff0000u);
        v[6] += asf(q1.y << 16); v[7] += asf(q1.y & 0xffff0000u);
        v[8] += asf(q2.x << 16); v[9] += asf(q2.x & 0xffff0000u);
        v[10] += asf(q2.y << 16); v[11] += asf(q2.y & 0xffff0000u);
    }
    #pragma unroll
    for (int m = 1; m < 64; m <<= 1){
        #pragma unroll
        for (int i = 0; i < 12; i++) v[i] += __shfl_xor(v[i], m, 64);
    }
    if (t == 0){
        float inv = 1.0f / (float)max(end - start - 1, 1);
        alp0[sp] = pack4(v[0]*inv, v[1]*inv, v[2]*inv,  v[3]*inv);
        alp1[sp] = pack4(v[4]*inv, v[5]*inv, v[6]*inv,  v[7]*inv);
        alp2[sp] = pack4(v[8]*inv, v[9]*inv, v[10]*inv, v[11]*inv);
    }
}

// ---------------- per-layer GEMM hh = h @ W via MFMA (bf16), fused a_s/a_d; hh stored fp8 e4m3 ----------------
__global__ __launch_bounds__(256) void gemm_hh_kernel(
        const float* __restrict__ h, const float* __restrict__ W,
        const float* __restrict__ att_s, const float* __restrict__ att_d,
        unsigned char* __restrict__ hh8, float* __restrict__ a_s,
        float* __restrict__ a_d)
{
    __shared__ __align__(16) unsigned char smem[128 * 136 * 2];   // 34816 B
    unsigned short* Wt = (unsigned short*)smem;                    // Wt[n*136 + k]
    float* Dsh = (float*)smem;                                     // Dsh[row*132 + col] (33792 B)
    int t = threadIdx.x;

    // stage W^T as bf16: Wt[n*136+k] = bf16(W[k*128+n])
    for (int i = t; i < 128 * 128; i += 256){
        int k = i >> 7, n = i & 127;
        Wt[n * 136 + k] = f2bf(W[i]);
    }
    __syncthreads();

    int wave = t >> 6, lane = t & 63;
    int mm = lane & 15, quad = lane >> 4;
    int row = blockIdx.x * GM_ROWS + wave * 16 + mm;
    int rclamp = min(row, N_NODES - 1);
    const float* hrow = h + (size_t)rclamp * HID;

    f32x4 acc[8];
    #pragma unroll
    for (int i = 0; i < 8; i++) acc[i] = (f32x4){0.f, 0.f, 0.f, 0.f};

    #pragma unroll
    for (int kc = 0; kc < 4; kc++){
        int k0 = kc * 32 + quad * 8;
        float4 a0 = *(const float4*)(hrow + k0);
        float4 a1 = *(const float4*)(hrow + k0 + 4);
        short8 af;
        af[0] = (short)f2bf(a0.x); af[1] = (short)f2bf(a0.y);
        af[2] = (short)f2bf(a0.z); af[3] = (short)f2bf(a0.w);
        af[4] = (short)f2bf(a1.x); af[5] = (short)f2bf(a1.y);
        af[6] = (short)f2bf(a1.z); af[7] = (short)f2bf(a1.w);
        #pragma unroll
        for (int nt = 0; nt < 8; nt++){
            short8 bf = *(const short8*)&Wt[(nt * 16 + mm) * 136 + k0];
            acc[nt] = __builtin_amdgcn_mfma_f32_16x16x32_bf16(af, bf, acc[nt], 0, 0, 0);
        }
    }
    __syncthreads();   // done reading Wt; reuse LDS as Dsh

    // D layout: lane holds D[m=quad*4+r][n=nt*16+mm]
    #pragma unroll
    for (int nt = 0; nt < 8; nt++){
        #pragma unroll
        for (int r = 0; r < 4; r++){
            Dsh[(wave * 16 + quad * 4 + r) * 132 + nt * 16 + mm] = acc[nt][r];
        }
    }
    __syncthreads();

    // epilogue: row parity by half-block; thread t -> col c; fp8 store + a_s/a_d
    int c = t & 127, rp = t >> 7;
    float as_w = att_s[c], ad_w = att_d[c];
    int head = c >> 5;
    for (int rr = rp; rr < GM_ROWS; rr += 2){
        int n = blockIdx.x * GM_ROWS + rr;
        if (n >= N_NODES) break;
        float val = Dsh[rr * 132 + c];
        unsigned int pk = (unsigned int)__builtin_amdgcn_cvt_pk_fp8_f32(val, 0.f, 0, false);
        hh8[(size_t)n * HID + c] = (unsigned char)(pk & 0xFFu);
        float vs = val * as_w, vd = val * ad_w;
        #pragma unroll
        for (int m2 = 16; m2 > 0; m2 >>= 1){
            vs += __shfl_xor(vs, m2, 32);
            vd += __shfl_xor(vd, m2, 32);
        }
        if ((c & 31) == 0){
            a_s[n * 4 + head] = vs;
            a_d[n * 4 + head] = vd;
        }
    }
}

// ---------------- fused single-WAVE agg: softmax + aggregate + residual + LN (no LDS, no barriers) ----------------
// 64 threads = 1 wave = 8 groups x 8 lanes; lane covers 16 channels (uint4 of fp8 hh).
__global__ __launch_bounds__(64) void agg_kernel(
        const float* __restrict__ a_s, const float* __restrict__ a_d,
        const int* __restrict__ row_ptr, const int2* __restrict__ csr_se,
        const uint2* __restrict__ alp, const uint4* __restrict__ hhv4,
        float* __restrict__ h, const float* __restrict__ gat_bias,
        const float* __restrict__ norm_g, const float* __restrict__ norm_b)
{
    int n = blockIdx.x, ln = threadIdx.x;
    int g = ln >> 3, l8 = ln & 7, hd = l8 >> 1;   // channels 16*l8 .. 16*l8+15, one head per lane
    int start = row_ptr[n], end = row_ptr[n + 1];
    float ad_h = a_d[n * 4 + hd];

    f32x2 accA[8], accB[8];
    #pragma unroll
    for (int i = 0; i < 8; i++){ accA[i] = (f32x2){0.f,0.f}; accB[i] = (f32x2){0.f,0.f}; }
    float exA = 0.f, exB = 0.f;

    auto step = [&](int pp, f32x2* acc, float& es){
        int2 se = csr_se[pp];
        uint2 av = alp[pp];
        float ae = bf2f(sel_head(av, hd));
        float x0 = a_s[se.x * 4 + hd] + ad_h + ae;
        x0 = x0 > 0.f ? x0 : 0.2f * x0;
        float e0 = __expf(x0);
        es += e0;
        uint4 q = hhv4[(size_t)se.x * 8 + l8];
        f32x2 ee = {e0, e0};
        acc[0] = __builtin_elementwise_fma(ee, __builtin_amdgcn_cvt_pk_f32_fp8(q.x, false), acc[0]);
        acc[1] = __builtin_elementwise_fma(ee, __builtin_amdgcn_cvt_pk_f32_fp8(q.x, true),  acc[1]);
        acc[2] = __builtin_elementwise_fma(ee, __builtin_amdgcn_cvt_pk_f32_fp8(q.y, false), acc[2]);
        acc[3] = __builtin_elementwise_fma(ee, __builtin_amdgcn_cvt_pk_f32_fp8(q.y, true),  acc[3]);
        acc[4] = __builtin_elementwise_fma(ee, __builtin_amdgcn_cvt_pk_f32_fp8(q.z, false), acc[4]);
        acc[5] = __builtin_elementwise_fma(ee, __builtin_amdgcn_cvt_pk_f32_fp8(q.z, true),  acc[5]);
        acc[6] = __builtin_elementwise_fma(ee, __builtin_amdgcn_cvt_pk_f32_fp8(q.w, false), acc[6]);
        acc[7] = __builtin_elementwise_fma(ee, __builtin_amdgcn_cvt_pk_f32_fp8(q.w, true),  acc[7]);
    };

    int p = start + g;
    for (; p + 8 < end; p += 16){
        step(p,     accA, exA);
        step(p + 8, accB, exB);
    }
    if (p < end) step(p, accA, exA);

    f32x2 acc[8];
    #pragma unroll
    for (int i = 0; i < 8; i++) acc[i] = accA[i] + accB[i];
    float ex = exA + exB;
    #pragma unroll
    for (int m = 8; m <= 32; m <<= 1){
        #pragma unroll
        for (int i = 0; i < 8; i++){
            acc[i].x += __shfl_xor(acc[i].x, m, 64);
            acc[i].y += __shfl_xor(acc[i].y, m, 64);
        }
        ex += __shfl_xor(ex, m, 64);
    }
    float invd = 1.0f / (ex + 1e-16f);

    // residual + bias; lane covers channels 16*l8..+15 (float4 x4)
    const float4* hrow4 = (const float4*)(h + (size_t)n * HID);
    const float4* bias4 = (const float4*)gat_bias;
    float y[16];
    #pragma unroll
    for (int j = 0; j < 4; j++){
        float4 hv = hrow4[l8 * 4 + j];
        float4 bv = bias4[l8 * 4 + j];
        y[j*4+0] = hv.x + acc[j*2+0].x * invd + bv.x;
        y[j*4+1] = hv.y + acc[j*2+0].y * invd + bv.y;
        y[j*4+2] = hv.z + acc[j*2+1].x * invd + bv.z;
        y[j*4+3] = hv.w + acc[j*2+1].y * invd + bv.w;
    }

    float s = 0.f;
    #pragma unroll
    for (int j = 0; j < 16; j++) s += y[j];
    #pragma unroll
    for (int m = 1; m <= 4; m <<= 1) s += __shfl_xor(s, m, 64);
    float mean = s * (1.0f / HID);
    float d[16];
    float vsum = 0.f;
    #pragma unroll
    for (int j = 0; j < 16; j++){ d[j] = y[j] - mean; vsum += d[j] * d[j]; }
    #pragma unroll
    for (int m = 1; m <= 4; m <<= 1) vsum += __shfl_xor(vsum, m, 64);
    float rstd = rsqrtf(vsum * (1.0f / HID) + 1e-5f);

    if (ln < 8){
        const float4* g4 = (const float4*)norm_g;
        const float4* b4 = (const float4*)norm_b;
        float4* orow = (float4*)(h + (size_t)n * HID);
        #pragma unroll
        for (int j = 0; j < 4; j++){
            float4 gg = g4[l8 * 4 + j];
            float4 bb = b4[l8 * 4 + j];
            float4 r;
            r.x = d[j*4+0] * rstd * gg.x + bb.x;
            r.y = d[j*4+1] * rstd * gg.y + bb.y;
            r.z = d[j*4+2] * rstd * gg.z + bb.z;
            r.w = d[j*4+3] * rstd * gg.w + bb.w;
            orow[l8 * 4 + j] = r;
        }
    }
}

// ---------------- pooling ----------------
__global__ void bounds_kernel(const int* __restrict__ batch, int* __restrict__ bstart){
    int b = threadIdx.x;
    if (b > NB) return;
    int lo = 0, hi = N_NODES;
    while (lo < hi){
        int mid = (lo + hi) >> 1;
        if (batch[mid] < b) lo = mid + 1; else hi = mid;
    }
    bstart[b] = lo;
}

__global__ void pool_kernel(const float* __restrict__ h, const int* __restrict__ bstart,
                            float* __restrict__ psum, float* __restrict__ pmax){
    int b = blockIdx.x, part = blockIdx.y, t = threadIdx.x;
    int s = bstart[b], e = bstart[b + 1];
    int len = e - s;
    int chunk = (len + PARTS - 1) / PARTS;
    int cs = s + part * chunk;
    int ce = min(cs + chunk, e);
    float sum = 0.f, mx = -FLT_MAX;
    for (int n = cs; n < ce; ++n){
        float v = h[(size_t)n * HID + t];
        sum += v; mx = fmaxf(mx, v);
    }
    int slot = (b * PARTS + part) * HID + t;
    psum[slot] = sum;
    pmax[slot] = mx;
}

// ---------------- readout MLP + sigmoid ----------------
__global__ void mlp_kernel(const float* __restrict__ psum, const float* __restrict__ pmax,
                           const int* __restrict__ bstart,
                           const float* __restrict__ fw1, const float* __restrict__ fb1,
                           const float* __restrict__ fw2, const float* __restrict__ fb2,
                           const float* __restrict__ cw1, const float* __restrict__ cb1,
                           const float* __restrict__ cw2, const float* __restrict__ cb2,
                           float* __restrict__ out)
{
    __shared__ float g[256];
    __shared__ float y1[128];
    __shared__ float y2[64];
    __shared__ float y3[64];
    __shared__ float red[2];
    int b = blockIdx.x, t = threadIdx.x;
    float sum = 0.f, mx = -FLT_MAX;
    for (int p = 0; p < PARTS; p++){
        int slot = (b * PARTS + p) * HID + t;
        sum += psum[slot];
        mx = fmaxf(mx, pmax[slot]);
    }
    int cnt = bstart[b + 1] - bstart[b];
    float mean = sum / (float)max(cnt, 1);
    if (cnt <= 0) mx = 0.f;
    g[t] = mean; g[128 + t] = mx;
    __syncthreads();
    float a1 = fb1[t];
    for (int k = 0; k < 256; k++) a1 += g[k] * fw1[k * 128 + t];
    y1[t] = gelu_f(a1);
    __syncthreads();
    if (t < 64){
        float a2 = fb2[t];
        for (int k = 0; k < 128; k++) a2 += y1[k] * fw2[k * 64 + t];
        y2[t] = gelu_f(a2);
    }
    __syncthreads();
    if (t < 64){
        float a3 = cb1[t];
        for (int k = 0; k < 64; k++) a3 += y2[k] * cw1[k * 64 + t];
        y3[t] = gelu_f(a3);
    }
    __syncthreads();
    float v = (t < 64) ? y3[t] * cw2[t] : 0.f;
    float s = blk_sum128(v, red);
    if (t == 0){
        float logit = s + cb2[0];
        out[b] = 1.0f / (1.0f + expf(-logit));
    }
}

extern "C" void kernel_launch(void* const* d_in, const int* in_sizes, int n_in,
                              void* d_out, int out_size, void* d_ws, size_t ws_size,
                              hipStream_t stream)
{
    const float* x         = (const float*)d_in[0];
    const float* edge_attr = (const float*)d_in[1];
    const int*   edge_idx  = (const int*)  d_in[2];
    const int*   batch     = (const int*)  d_in[3];
    const float* enc_w     = (const float*)d_in[4];
    const float* enc_b     = (const float*)d_in[5];
    const float* enc_g     = (const float*)d_in[6];
    const float* enc_beta  = (const float*)d_in[7];
    const float* ee_w      = (const float*)d_in[8];
    const float* ee_b      = (const float*)d_in[9];
    const float* gat_lin_w = (const float*)d_in[10];
    const float* gat_edge_w= (const float*)d_in[11];
    const float* att_src   = (const float*)d_in[12];
    const float* att_dst   = (const float*)d_in[13];
    const float* att_edge  = (const float*)d_in[14];
    const float* gat_bias  = (const float*)d_in[15];
    const float* norm_g    = (const float*)d_in[16];
    const float* norm_b    = (const float*)d_in[17];
    const float* fw1       = (const float*)d_in[18];
    const float* fb1       = (const float*)d_in[19];
    const float* fw2       = (const float*)d_in[20];
    const float* fb2       = (const float*)d_in[21];
    const float* cw1       = (const float*)d_in[22];
    const float* cb1       = (const float*)d_in[23];
    const float* cw2       = (const float*)d_in[24];
    const float* cb2       = (const float*)d_in[25];
    float* out = (float*)d_out;

    char* wsp = (char*)d_ws;
    size_t off = 0;
    auto alloc = [&](size_t bytes) -> void* {
        void* p = wsp + off;
        off += (bytes + 255) & ~(size_t)255;
        return p;
    };
    float*          h        = (float*)alloc((size_t)N_NODES * HID * 4);
    unsigned char*  hh8      = (unsigned char*)alloc((size_t)N_NODES * HID);
    float*          a_s      = (float*)alloc((size_t)N_NODES * 4 * 4);
    float*          a_d      = (float*)alloc((size_t)N_NODES * 4 * 4);
    uint2*          alp0     = (uint2*)alloc((size_t)TOT * 8);
    uint2*          alp1     = (uint2*)alloc((size_t)TOT * 8);
    uint2*          alp2     = (uint2*)alloc((size_t)TOT * 8);
    int2*           csr_se   = (int2*) alloc((size_t)TOT * 8);
    int*            self_pos = (int*)  alloc((size_t)N_NODES * 4);
    int*            row_ptr  = (int*)  alloc((size_t)(N_NODES + 1) * 4);
    int*            cursor   = (int*)  alloc((size_t)N_NODES * 4);
    int*            row_count= (int*)  alloc((size_t)N_NODES * 4);
    int*            bsum     = (int*)  alloc((size_t)SCAN_NB * 4);
    float*          We3      = (float*)alloc(3 * 64 * 4 * 4);
    int*            bstart   = (int*)  alloc((NB + 1) * 4);
    float*          psum     = (float*)alloc((size_t)NB * PARTS * HID * 4);
    float*          pmax     = (float*)alloc((size_t)NB * PARTS * HID * 4);

    // encoder
    hipLaunchKernelGGL(enc_kernel, dim3(N_NODES), dim3(128), 0, stream,
                       x, enc_w, enc_b, enc_g, enc_beta, h);

    // CSR build (partitioned count + multi-block scan + partitioned scatter)
    hipMemsetAsync(row_count, 0, (size_t)N_NODES * 4, stream);
    {
        int slices_c = (N_EDGES + EPB - 1) / EPB;
        hipLaunchKernelGGL(count_kernel, dim3(slices_c * NPART), dim3(256), 0, stream,
                           edge_idx, row_count);
    }
    hipLaunchKernelGGL(scan1_kernel, dim3(SCAN_NB), dim3(256), 0, stream, row_count, bsum);
    hipLaunchKernelGGL(scan2_kernel, dim3(1), dim3(256), 0, stream, bsum);
    hipLaunchKernelGGL(scan3_kernel, dim3(SCAN_NB), dim3(256), 0, stream,
                       row_count, bsum, row_ptr, cursor);
    {
        int slices_s = (TOT + EPB - 1) / EPB;
        hipLaunchKernelGGL(scatter_kernel, dim3(slices_s * NPART), dim3(256), 0, stream,
                           edge_idx, cursor, csr_se, self_pos, alp0, alp1, alp2);
    }

    // all-layer edge attention terms, CSR-position order (coalesced writes + reads in agg)
    hipLaunchKernelGGL(we3_kernel, dim3(1), dim3(256), 0, stream, gat_edge_w, att_edge, We3);
    hipLaunchKernelGGL(ae_pos_kernel, dim3((TOT + 255) / 256), dim3(256), 0, stream,
                       (const int2*)csr_se, (const float4*)edge_attr, ee_w, ee_b, We3,
                       alp0, alp1, alp2);
    hipLaunchKernelGGL(selfae_kernel, dim3(N_NODES), dim3(64), 0, stream,
                       row_ptr, self_pos, alp0, alp1, alp2);

    // GAT layers
    uint2* alps[3] = {alp0, alp1, alp2};
    int gemm_blocks = (N_NODES + GM_ROWS - 1) / GM_ROWS;
    for (int l = 0; l < 3; l++){
        hipLaunchKernelGGL(gemm_hh_kernel, dim3(gemm_blocks), dim3(256), 0, stream,
                           h, gat_lin_w + (size_t)l * HID * HID,
                           att_src + (size_t)l * HID, att_dst + (size_t)l * HID,
                           hh8, a_s, a_d);
        hipLaunchKernelGGL(agg_kernel, dim3(N_NODES), dim3(64), 0, stream,
                           a_s, a_d, row_ptr, (const int2*)csr_se,
                           (const uint2*)alps[l], (const uint4*)hh8, h,
                           gat_bias + (size_t)l * HID, norm_g + (size_t)l * HID,
                           norm_b + (size_t)l * HID);
    }

    // pooling + MLP
    hipLaunchKernelGGL(bounds_kernel, dim3(1), dim3(128), 0, stream, batch, bstart);
    hipLaunchKernelGGL(pool_kernel, dim3(NB, PARTS), dim3(128), 0, stream, h, bstart, psum, pmax);
    hipLaunchKernelGGL(mlp_kernel, dim3(NB), dim3(128), 0, stream,
                       psum, pmax, bstart, fw1, fb1, fw2, fb2, cw1, cb1, cw2, cb2, out);
}

// Round 12
// 641.380 us; speedup vs baseline: 1.1185x; 1.1185x over previous
//
#include <hip/hip_runtime.h>
#include <float.h>
#include <math.h>

#define N_NODES 50000
#define N_EDGES 1600000
#define NB      64
#define HID     128
#define TOT     (N_EDGES + N_NODES)
#define PARTS   16
#define SCAN_NB 196   // ceil(50000/256)
#define NPART4  4
#define PSIZE4  12500 // 50000/4
#define SEPB    2048  // edges per block in partitioned scatter
#define GM_ROWS 64    // rows per block in MFMA gemm

typedef __attribute__((ext_vector_type(8))) short short8;
typedef __attribute__((ext_vector_type(4))) float f32x4;
typedef __attribute__((ext_vector_type(2))) float f32x2;

__device__ __forceinline__ float gelu_f(float x){
    return 0.5f * x * (1.0f + erff(x * 0.70710678118654752440f));
}

__device__ __forceinline__ float asf(unsigned int u){
    union { unsigned int i; float f; } c; c.i = u; return c.f;
}
__device__ __forceinline__ float bf2f(unsigned short u){
    return asf(((unsigned int)u) << 16);
}
__device__ __forceinline__ unsigned short f2bf(float x){
    union { float f; unsigned int i; } c; c.f = x;
    unsigned int r = c.i + 0x7fffu + ((c.i >> 16) & 1u);
    return (unsigned short)(r >> 16);
}
__device__ __forceinline__ uint2 pack4(float a, float b, float cc, float d){
    uint2 r;
    r.x = (unsigned int)f2bf(a) | ((unsigned int)f2bf(b) << 16);
    r.y = (unsigned int)f2bf(cc) | ((unsigned int)f2bf(d) << 16);
    return r;
}
__device__ __forceinline__ unsigned short sel_head(uint2 v, int hd){
    return (hd & 2) ? ((hd & 1) ? (unsigned short)(v.y >> 16) : (unsigned short)(v.y & 0xffff))
                    : ((hd & 1) ? (unsigned short)(v.x >> 16) : (unsigned short)(v.x & 0xffff));
}

// block of 128 threads (2 waves) sum-reduce; red must be float[>=2] shared
__device__ __forceinline__ float blk_sum128(float v, float* red){
    #pragma unroll
    for (int m = 32; m > 0; m >>= 1) v += __shfl_xor(v, m, 64);
    __syncthreads();
    if ((threadIdx.x & 63) == 0) red[threadIdx.x >> 6] = v;
    __syncthreads();
    float r = red[0] + red[1];
    __syncthreads();
    return r;
}

// inclusive scan across 256 threads; wsum must be int[4] shared
__device__ __forceinline__ int blk_scan256(int v, int* wsum){
    int t = threadIdx.x, lane = t & 63, w = t >> 6;
    int x = v;
    #pragma unroll
    for (int off = 1; off < 64; off <<= 1){
        int y = __shfl_up(x, off, 64);
        if (lane >= off) x += y;
    }
    if (lane == 63) wsum[w] = x;
    __syncthreads();
    if (t == 0){
        int s = 0;
        #pragma unroll
        for (int i = 0; i < 4; i++){ int tmp = wsum[i]; wsum[i] = s; s += tmp; }
    }
    __syncthreads();
    return x + wsum[w];
}

// ---------------- encoder: h = gelu(LN(x@enc_w+enc_b)) ----------------
__global__ void enc_kernel(const float* __restrict__ x, const float* __restrict__ enc_w,
                           const float* __restrict__ enc_b, const float* __restrict__ enc_g,
                           const float* __restrict__ enc_beta, float* __restrict__ h)
{
    __shared__ float xs[12];
    __shared__ float red[2];
    int n = blockIdx.x, t = threadIdx.x;
    if (t < 12) xs[t] = x[n * 12 + t];
    __syncthreads();
    float acc = enc_b[t];
    #pragma unroll
    for (int k = 0; k < 12; k++) acc += xs[k] * enc_w[k * HID + t];
    float mean = blk_sum128(acc, red) * (1.0f / HID);
    float d = acc - mean;
    float var = blk_sum128(d * d, red) * (1.0f / HID);
    float y = d * rsqrtf(var + 1e-5f) * enc_g[t] + enc_beta[t];
    h[(size_t)n * HID + t] = gelu_f(y);
}

// ---------------- CSR build: single-pass rank + scan + atomic-free partitioned scatter ----------------
__global__ void rank_kernel(const int* __restrict__ ei, int* __restrict__ row_count,
                            int* __restrict__ rank){
    int i = blockIdx.x * 256 + threadIdx.x;
    if (i < N_EDGES) rank[i] = atomicAdd(&row_count[ei[N_EDGES + i]], 1);
}

// per-block totals of (count+1)
__global__ void scan1_kernel(const int* __restrict__ row_count, int* __restrict__ bsum){
    __shared__ int ws[4];
    int i = blockIdx.x * 256 + threadIdx.x;
    int v = (i < N_NODES) ? (row_count[i] + 1) : 0;
    int x = v;
    #pragma unroll
    for (int m = 32; m > 0; m >>= 1) x += __shfl_xor(x, m, 64);
    if ((threadIdx.x & 63) == 0) ws[threadIdx.x >> 6] = x;
    __syncthreads();
    if (threadIdx.x == 0) bsum[blockIdx.x] = ws[0] + ws[1] + ws[2] + ws[3];
}

// exclusive scan of the 196 block sums (single small block)
__global__ void scan2_kernel(int* __restrict__ bsum){
    __shared__ int ws[4];
    int t = threadIdx.x;
    int v = (t < SCAN_NB) ? bsum[t] : 0;
    int incl = blk_scan256(v, ws);
    if (t < SCAN_NB) bsum[t] = incl - v;   // exclusive
}

// per-block rescan + offset -> row_ptr; also writes the self-loop CSR entry
// (deterministic position row_ptr[n+1]-1) and zeroes its alp records.
__global__ void scan3_kernel(const int* __restrict__ row_count, const int* __restrict__ bsum,
                             int* __restrict__ row_ptr, int2* __restrict__ csr_se,
                             uint2* __restrict__ alp0, uint2* __restrict__ alp1,
                             uint2* __restrict__ alp2){
    __shared__ int ws[4];
    int i = blockIdx.x * 256 + threadIdx.x;
    int v = (i < N_NODES) ? (row_count[i] + 1) : 0;
    int incl = blk_scan256(v, ws) + bsum[blockIdx.x];
    if (i < N_NODES){
        row_ptr[i + 1] = incl;
        int sp = incl - 1;
        csr_se[sp] = make_int2(i, N_EDGES);   // self-loop record (eid >= N_EDGES marker)
        uint2 z = make_uint2(0u, 0u);
        alp0[sp] = z; alp1[sp] = z; alp2[sp] = z;
    }
    if (i == 0) row_ptr[0] = 0;
}

// atomic-free partitioned scatter: pos = row_ptr[d] + rank[e]
__global__ void scatter_kernel(const int* __restrict__ ei, const int* __restrict__ rank,
                               const int* __restrict__ row_ptr, int2* __restrict__ csr_se){
    int part = blockIdx.x & (NPART4 - 1);
    int slice = blockIdx.x >> 2;
    int lo = part * PSIZE4, hi = lo + PSIZE4;
    int base = slice * SEPB;
    int iend = min(base + SEPB, N_EDGES);
    for (int i = base + threadIdx.x; i < iend; i += 256){
        int d = ei[N_EDGES + i];
        if (d < lo || d >= hi) continue;
        int pos = row_ptr[d] + rank[i];
        csr_se[pos] = make_int2(ei[i], i);
    }
}

// ---------------- We3[l][k][h] = sum_c gat_edge_w[l][k][h*32+c]*att_edge[l][h*32+c] ----------------
__global__ void we3_kernel(const float* __restrict__ gat_edge_w, const float* __restrict__ att_edge,
                           float* __restrict__ We3)
{
    int t = threadIdx.x;          // 256 threads
    int k = t >> 2, hd = t & 3;
    for (int l = 0; l < 3; l++){
        float s = 0.f;
        #pragma unroll
        for (int c = 0; c < 32; c++)
            s += gat_edge_w[(size_t)l * 64 * HID + k * HID + hd * 32 + c]
               * att_edge[l * HID + hd * 32 + c];
        We3[(l * 64 + k) * 4 + hd] = s;
    }
}

// ---------------- per-position a_e for ALL 3 layers, CSR ORDER ----------------
// pk-paired sigmoid-form gelu: gelu_tanh(x) = x * rcp(1 + exp2(-2.3021182*x*(1+0.044715x^2)))
__global__ void ae_pos_kernel(const int2* __restrict__ csr_se, const float4* __restrict__ edge_attr,
                              const float* __restrict__ ee_w, const float* __restrict__ ee_b,
                              const float* __restrict__ We3,
                              uint2* __restrict__ alp0, uint2* __restrict__ alp1,
                              uint2* __restrict__ alp2)
{
    int p = blockIdx.x * 256 + threadIdx.x;
    if (p >= TOT) return;
    int2 se = csr_se[p];
    if (se.y >= N_EDGES) return;             // self-loop positions stay zero (filled by selfae)
    float4 ea = edge_attr[se.y];
    const f32x2* w0 = (const f32x2*)(ee_w);
    const f32x2* w1 = (const f32x2*)(ee_w + 64);
    const f32x2* w2 = (const f32x2*)(ee_w + 128);
    const f32x2* w3 = (const f32x2*)(ee_w + 192);
    const f32x2* bb = (const f32x2*)(ee_b);
    const f32x2* Wv = (const f32x2*)(We3);   // Wv[(l*64+k)*2 + {0,1}]

    f32x2 eax = {ea.x, ea.x}, eay = {ea.y, ea.y}, eaz = {ea.z, ea.z}, eaw = {ea.w, ea.w};
    const f32x2 one2 = {1.0f, 1.0f};
    const f32x2 c044 = {0.044715f, 0.044715f};
    const f32x2 kneg = {-2.3021182f, -2.3021182f};   // -2 * 0.7978845608 * log2(e)

    f32x2 acc[6];
    #pragma unroll
    for (int i = 0; i < 6; i++) acc[i] = (f32x2){0.f, 0.f};

    #pragma unroll 4
    for (int m = 0; m < 32; m++){
        f32x2 u = bb[m];
        u = __builtin_elementwise_fma(eax, w0[m], u);
        u = __builtin_elementwise_fma(eay, w1[m], u);
        u = __builtin_elementwise_fma(eaz, w2[m], u);
        u = __builtin_elementwise_fma(eaw, w3[m], u);
        f32x2 a = u * u;
        f32x2 b = __builtin_elementwise_fma(c044, a, one2);
        f32x2 c = u * kneg;
        f32x2 z = c * b;
        f32x2 e = { __builtin_amdgcn_exp2f(z.x), __builtin_amdgcn_exp2f(z.y) };
        f32x2 d = e + one2;
        f32x2 r = { __builtin_amdgcn_rcpf(d.x), __builtin_amdgcn_rcpf(d.y) };
        f32x2 g = u * r;
        f32x2 gx = {g.x, g.x}, gy = {g.y, g.y};
        #pragma unroll
        for (int l = 0; l < 3; l++){
            int base = (l * 64 + 2 * m) * 2;
            acc[l*2+0] = __builtin_elementwise_fma(gx, Wv[base + 0], acc[l*2+0]);
            acc[l*2+1] = __builtin_elementwise_fma(gx, Wv[base + 1], acc[l*2+1]);
            acc[l*2+0] = __builtin_elementwise_fma(gy, Wv[base + 2], acc[l*2+0]);
            acc[l*2+1] = __builtin_elementwise_fma(gy, Wv[base + 3], acc[l*2+1]);
        }
    }
    alp0[p] = pack4(acc[0].x, acc[0].y, acc[1].x, acc[1].y);
    alp1[p] = pack4(acc[2].x, acc[2].y, acc[3].x, acc[3].y);
    alp2[p] = pack4(acc[4].x, acc[4].y, acc[5].x, acc[5].y);
}

// ---------------- self-loop a_e = mean of row's real-edge a_e (self slot = end-1, pre-zeroed) ----------------
__global__ __launch_bounds__(64) void selfae_kernel(
        const int* __restrict__ row_ptr,
        uint2* __restrict__ alp0, uint2* __restrict__ alp1, uint2* __restrict__ alp2)
{
    int n = blockIdx.x, t = threadIdx.x;   // 64 threads = 1 wave
    int start = row_ptr[n], end = row_ptr[n + 1];
    int sp = end - 1;
    float v[12];
    #pragma unroll
    for (int i = 0; i < 12; i++) v[i] = 0.f;
    for (int p = start + t; p < end; p += 64){
        uint2 q0 = alp0[p], q1 = alp1[p], q2 = alp2[p];
        v[0] += asf(q0.x << 16); v[1] += asf(q0.x & 0xffff0000u);
        v[2] += asf(q0.y << 16); v[3] += asf(q0.y & 0xffff0000u);
        v[4] += asf(q1.x << 16); v[5] += asf(q1.x & 0xffff0000u);
        v[6] += asf(q1.y << 16); v[7] += asf(q1.y & 0xffff0000u);
        v[8] += asf(q2.x << 16); v[9] += asf(q2.x & 0xffff0000u);
        v[10] += asf(q2.y << 16); v[11] += asf(q2.y & 0xffff0000u);
    }
    #pragma unroll
    for (int m = 1; m < 64; m <<= 1){
        #pragma unroll
        for (int i = 0; i < 12; i++) v[i] += __shfl_xor(v[i], m, 64);
    }
    if (t == 0){
        float inv = 1.0f / (float)max(end - start - 1, 1);
        alp0[sp] = pack4(v[0]*inv, v[1]*inv, v[2]*inv,  v[3]*inv);
        alp1[sp] = pack4(v[4]*inv, v[5]*inv, v[6]*inv,  v[7]*inv);
        alp2[sp] = pack4(v[8]*inv, v[9]*inv, v[10]*inv, v[11]*inv);
    }
}

// ---------------- per-layer GEMM hh = h @ W via MFMA (bf16), fused a_s/a_d; hh stored fp8 e4m3 ----------------
__global__ __launch_bounds__(256) void gemm_hh_kernel(
        const float* __restrict__ h, const float* __restrict__ W,
        const float* __restrict__ att_s, const float* __restrict__ att_d,
        unsigned char* __restrict__ hh8, float* __restrict__ a_s,
        float* __restrict__ a_d)
{
    __shared__ __align__(16) unsigned char smem[128 * 136 * 2];   // 34816 B
    unsigned short* Wt = (unsigned short*)smem;                    // Wt[n*136 + k]
    float* Dsh = (float*)smem;                                     // Dsh[row*132 + col] (33792 B)
    int t = threadIdx.x;

    // stage W^T as bf16: Wt[n*136+k] = bf16(W[k*128+n])
    for (int i = t; i < 128 * 128; i += 256){
        int k = i >> 7, n = i & 127;
        Wt[n * 136 + k] = f2bf(W[i]);
    }
    __syncthreads();

    int wave = t >> 6, lane = t & 63;
    int mm = lane & 15, quad = lane >> 4;
    int row = blockIdx.x * GM_ROWS + wave * 16 + mm;
    int rclamp = min(row, N_NODES - 1);
    const float* hrow = h + (size_t)rclamp * HID;

    f32x4 acc[8];
    #pragma unroll
    for (int i = 0; i < 8; i++) acc[i] = (f32x4){0.f, 0.f, 0.f, 0.f};

    #pragma unroll
    for (int kc = 0; kc < 4; kc++){
        int k0 = kc * 32 + quad * 8;
        float4 a0 = *(const float4*)(hrow + k0);
        float4 a1 = *(const float4*)(hrow + k0 + 4);
        short8 af;
        af[0] = (short)f2bf(a0.x); af[1] = (short)f2bf(a0.y);
        af[2] = (short)f2bf(a0.z); af[3] = (short)f2bf(a0.w);
        af[4] = (short)f2bf(a1.x); af[5] = (short)f2bf(a1.y);
        af[6] = (short)f2bf(a1.z); af[7] = (short)f2bf(a1.w);
        #pragma unroll
        for (int nt = 0; nt < 8; nt++){
            short8 bf = *(const short8*)&Wt[(nt * 16 + mm) * 136 + k0];
            acc[nt] = __builtin_amdgcn_mfma_f32_16x16x32_bf16(af, bf, acc[nt], 0, 0, 0);
        }
    }
    __syncthreads();   // done reading Wt; reuse LDS as Dsh

    // D layout: lane holds D[m=quad*4+r][n=nt*16+mm]
    #pragma unroll
    for (int nt = 0; nt < 8; nt++){
        #pragma unroll
        for (int r = 0; r < 4; r++){
            Dsh[(wave * 16 + quad * 4 + r) * 132 + nt * 16 + mm] = acc[nt][r];
        }
    }
    __syncthreads();

    // epilogue: row parity by half-block; thread t -> col c; fp8 store + a_s/a_d
    int c = t & 127, rp = t >> 7;
    float as_w = att_s[c], ad_w = att_d[c];
    int head = c >> 5;
    for (int rr = rp; rr < GM_ROWS; rr += 2){
        int n = blockIdx.x * GM_ROWS + rr;
        if (n >= N_NODES) break;
        float val = Dsh[rr * 132 + c];
        unsigned int pk = (unsigned int)__builtin_amdgcn_cvt_pk_fp8_f32(val, 0.f, 0, false);
        hh8[(size_t)n * HID + c] = (unsigned char)(pk & 0xFFu);
        float vs = val * as_w, vd = val * ad_w;
        #pragma unroll
        for (int m2 = 16; m2 > 0; m2 >>= 1){
            vs += __shfl_xor(vs, m2, 32);
            vd += __shfl_xor(vd, m2, 32);
        }
        if ((c & 31) == 0){
            a_s[n * 4 + head] = vs;
            a_d[n * 4 + head] = vd;
        }
    }
}

// ---------------- fused single-WAVE agg: softmax + aggregate + residual + LN (no LDS, no barriers) ----------------
// 64 threads = 1 wave = 4 groups x 16 lanes; lane covers 8 channels (uint2 of fp8 hh).
__global__ __launch_bounds__(64) void agg_kernel(
        const float* __restrict__ a_s, const float* __restrict__ a_d,
        const int* __restrict__ row_ptr, const int2* __restrict__ csr_se,
        const uint2* __restrict__ alp, const uint2* __restrict__ hhv2,
        float* __restrict__ h, const float* __restrict__ gat_bias,
        const float* __restrict__ norm_g, const float* __restrict__ norm_b)
{
    int n = blockIdx.x, ln = threadIdx.x;
    int g = ln >> 4, l16 = ln & 15, hd = l16 >> 2;
    int start = row_ptr[n], end = row_ptr[n + 1];
    float ad_h = a_d[n * 4 + hd];

    f32x2 a01A = {0.f,0.f}, a23A = {0.f,0.f}, a45A = {0.f,0.f}, a67A = {0.f,0.f};
    f32x2 a01B = {0.f,0.f}, a23B = {0.f,0.f}, a45B = {0.f,0.f}, a67B = {0.f,0.f};
    float exA = 0.f, exB = 0.f;

    auto step = [&](int pp, f32x2& a01, f32x2& a23, f32x2& a45, f32x2& a67, float& es){
        int2 se = csr_se[pp];
        uint2 av = alp[pp];
        float ae = bf2f(sel_head(av, hd));
        float x0 = a_s[se.x * 4 + hd] + ad_h + ae;
        x0 = x0 > 0.f ? x0 : 0.2f * x0;
        float e0 = __expf(x0);
        es += e0;
        uint2 q = hhv2[(size_t)se.x * 16 + l16];
        f32x2 c01 = __builtin_amdgcn_cvt_pk_f32_fp8(q.x, false);
        f32x2 c23 = __builtin_amdgcn_cvt_pk_f32_fp8(q.x, true);
        f32x2 c45 = __builtin_amdgcn_cvt_pk_f32_fp8(q.y, false);
        f32x2 c67 = __builtin_amdgcn_cvt_pk_f32_fp8(q.y, true);
        f32x2 ee = {e0, e0};
        a01 = __builtin_elementwise_fma(ee, c01, a01);
        a23 = __builtin_elementwise_fma(ee, c23, a23);
        a45 = __builtin_elementwise_fma(ee, c45, a45);
        a67 = __builtin_elementwise_fma(ee, c67, a67);
    };

    int p = start + g;
    for (; p + 4 < end; p += 8){
        step(p,     a01A, a23A, a45A, a67A, exA);
        step(p + 4, a01B, a23B, a45B, a67B, exB);
    }
    if (p < end) step(p, a01A, a23A, a45A, a67A, exA);

    f32x2 a01 = a01A + a01B, a23 = a23A + a23B, a45 = a45A + a45B, a67 = a67A + a67B;
    float ex = exA + exB;
    #pragma unroll
    for (int m = 16; m <= 32; m <<= 1){
        a01.x += __shfl_xor(a01.x, m, 64); a01.y += __shfl_xor(a01.y, m, 64);
        a23.x += __shfl_xor(a23.x, m, 64); a23.y += __shfl_xor(a23.y, m, 64);
        a45.x += __shfl_xor(a45.x, m, 64); a45.y += __shfl_xor(a45.y, m, 64);
        a67.x += __shfl_xor(a67.x, m, 64); a67.y += __shfl_xor(a67.y, m, 64);
        ex += __shfl_xor(ex, m, 64);
    }
    float invd = 1.0f / (ex + 1e-16f);

    const float4* hrow4 = (const float4*)(h + (size_t)n * HID);
    float4 hv0 = hrow4[l16 * 2], hv1 = hrow4[l16 * 2 + 1];
    float4 b0 = ((const float4*)gat_bias)[l16 * 2];
    float4 b1 = ((const float4*)gat_bias)[l16 * 2 + 1];
    float y0 = hv0.x + a01.x * invd + b0.x;
    float y1 = hv0.y + a01.y * invd + b0.y;
    float y2 = hv0.z + a23.x * invd + b0.z;
    float y3 = hv0.w + a23.y * invd + b0.w;
    float y4 = hv1.x + a45.x * invd + b1.x;
    float y5 = hv1.y + a45.y * invd + b1.y;
    float y6 = hv1.z + a67.x * invd + b1.z;
    float y7 = hv1.w + a67.y * invd + b1.w;

    float s = y0 + y1 + y2 + y3 + y4 + y5 + y6 + y7;
    #pragma unroll
    for (int m = 1; m <= 8; m <<= 1) s += __shfl_xor(s, m, 64);
    float mean = s * (1.0f / HID);
    float d0 = y0 - mean, d1 = y1 - mean, d2 = y2 - mean, d3 = y3 - mean;
    float d4 = y4 - mean, d5 = y5 - mean, d6 = y6 - mean, d7 = y7 - mean;
    float vsum = d0*d0 + d1*d1 + d2*d2 + d3*d3 + d4*d4 + d5*d5 + d6*d6 + d7*d7;
    #pragma unroll
    for (int m = 1; m <= 8; m <<= 1) vsum += __shfl_xor(vsum, m, 64);
    float rstd = rsqrtf(vsum * (1.0f / HID) + 1e-5f);

    if (ln < 16){
        float4 g0 = ((const float4*)norm_g)[l16 * 2];
        float4 g1 = ((const float4*)norm_g)[l16 * 2 + 1];
        float4 nb0 = ((const float4*)norm_b)[l16 * 2];
        float4 nb1 = ((const float4*)norm_b)[l16 * 2 + 1];
        float4 r0 = make_float4(d0 * rstd * g0.x + nb0.x, d1 * rstd * g0.y + nb0.y,
                                d2 * rstd * g0.z + nb0.z, d3 * rstd * g0.w + nb0.w);
        float4 r1 = make_float4(d4 * rstd * g1.x + nb1.x, d5 * rstd * g1.y + nb1.y,
                                d6 * rstd * g1.z + nb1.z, d7 * rstd * g1.w + nb1.w);
        float4* orow = (float4*)(h + (size_t)n * HID);
        orow[l16 * 2] = r0;
        orow[l16 * 2 + 1] = r1;
    }
}

// ---------------- pooling ----------------
__global__ void bounds_kernel(const int* __restrict__ batch, int* __restrict__ bstart){
    int b = threadIdx.x;
    if (b > NB) return;
    int lo = 0, hi = N_NODES;
    while (lo < hi){
        int mid = (lo + hi) >> 1;
        if (batch[mid] < b) lo = mid + 1; else hi = mid;
    }
    bstart[b] = lo;
}

__global__ void pool_kernel(const float* __restrict__ h, const int* __restrict__ bstart,
                            float* __restrict__ psum, float* __restrict__ pmax){
    int b = blockIdx.x, part = blockIdx.y, t = threadIdx.x;
    int s = bstart[b], e = bstart[b + 1];
    int len = e - s;
    int chunk = (len + PARTS - 1) / PARTS;
    int cs = s + part * chunk;
    int ce = min(cs + chunk, e);
    float sum = 0.f, mx = -FLT_MAX;
    for (int n = cs; n < ce; ++n){
        float v = h[(size_t)n * HID + t];
        sum += v; mx = fmaxf(mx, v);
    }
    int slot = (b * PARTS + part) * HID + t;
    psum[slot] = sum;
    pmax[slot] = mx;
}

// ---------------- readout MLP + sigmoid ----------------
__global__ void mlp_kernel(const float* __restrict__ psum, const float* __restrict__ pmax,
                           const int* __restrict__ bstart,
                           const float* __restrict__ fw1, const float* __restrict__ fb1,
                           const float* __restrict__ fw2, const float* __restrict__ fb2,
                           const float* __restrict__ cw1, const float* __restrict__ cb1,
                           const float* __restrict__ cw2, const float* __restrict__ cb2,
                           float* __restrict__ out)
{
    __shared__ float g[256];
    __shared__ float y1[128];
    __shared__ float y2[64];
    __shared__ float y3[64];
    __shared__ float red[2];
    int b = blockIdx.x, t = threadIdx.x;
    float sum = 0.f, mx = -FLT_MAX;
    for (int p = 0; p < PARTS; p++){
        int slot = (b * PARTS + p) * HID + t;
        sum += psum[slot];
        mx = fmaxf(mx, pmax[slot]);
    }
    int cnt = bstart[b + 1] - bstart[b];
    float mean = sum / (float)max(cnt, 1);
    if (cnt <= 0) mx = 0.f;
    g[t] = mean; g[128 + t] = mx;
    __syncthreads();
    float a1 = fb1[t];
    for (int k = 0; k < 256; k++) a1 += g[k] * fw1[k * 128 + t];
    y1[t] = gelu_f(a1);
    __syncthreads();
    if (t < 64){
        float a2 = fb2[t];
        for (int k = 0; k < 128; k++) a2 += y1[k] * fw2[k * 64 + t];
        y2[t] = gelu_f(a2);
    }
    __syncthreads();
    if (t < 64){
        float a3 = cb1[t];
        for (int k = 0; k < 64; k++) a3 += y2[k] * cw1[k * 64 + t];
        y3[t] = gelu_f(a3);
    }
    __syncthreads();
    float v = (t < 64) ? y3[t] * cw2[t] : 0.f;
    float s = blk_sum128(v, red);
    if (t == 0){
        float logit = s + cb2[0];
        out[b] = 1.0f / (1.0f + expf(-logit));
    }
}

extern "C" void kernel_launch(void* const* d_in, const int* in_sizes, int n_in,
                              void* d_out, int out_size, void* d_ws, size_t ws_size,
                              hipStream_t stream)
{
    const float* x         = (const float*)d_in[0];
    const float* edge_attr = (const float*)d_in[1];
    const int*   edge_idx  = (const int*)  d_in[2];
    const int*   batch     = (const int*)  d_in[3];
    const float* enc_w     = (const float*)d_in[4];
    const float* enc_b     = (const float*)d_in[5];
    const float* enc_g     = (const float*)d_in[6];
    const float* enc_beta  = (const float*)d_in[7];
    const float* ee_w      = (const float*)d_in[8];
    const float* ee_b      = (const float*)d_in[9];
    const float* gat_lin_w = (const float*)d_in[10];
    const float* gat_edge_w= (const float*)d_in[11];
    const float* att_src   = (const float*)d_in[12];
    const float* att_dst   = (const float*)d_in[13];
    const float* att_edge  = (const float*)d_in[14];
    const float* gat_bias  = (const float*)d_in[15];
    const float* norm_g    = (const float*)d_in[16];
    const float* norm_b    = (const float*)d_in[17];
    const float* fw1       = (const float*)d_in[18];
    const float* fb1       = (const float*)d_in[19];
    const float* fw2       = (const float*)d_in[20];
    const float* fb2       = (const float*)d_in[21];
    const float* cw1       = (const float*)d_in[22];
    const float* cb1       = (const float*)d_in[23];
    const float* cw2       = (const float*)d_in[24];
    const float* cb2       = (const float*)d_in[25];
    float* out = (float*)d_out;

    char* wsp = (char*)d_ws;
    size_t off = 0;
    auto alloc = [&](size_t bytes) -> void* {
        void* p = wsp + off;
        off += (bytes + 255) & ~(size_t)255;
        return p;
    };
    float*          h        = (float*)alloc((size_t)N_NODES * HID * 4);
    unsigned char*  hh8      = (unsigned char*)alloc((size_t)N_NODES * HID);
    float*          a_s      = (float*)alloc((size_t)N_NODES * 4 * 4);
    float*          a_d      = (float*)alloc((size_t)N_NODES * 4 * 4);
    uint2*          alp0     = (uint2*)alloc((size_t)TOT * 8);
    uint2*          alp1     = (uint2*)alloc((size_t)TOT * 8);
    uint2*          alp2     = (uint2*)alloc((size_t)TOT * 8);
    int2*           csr_se   = (int2*) alloc((size_t)TOT * 8);
    int*            rank     = (int*)  alloc((size_t)N_EDGES * 4);
    int*            row_ptr  = (int*)  alloc((size_t)(N_NODES + 1) * 4);
    int*            row_count= (int*)  alloc((size_t)N_NODES * 4);
    int*            bsum     = (int*)  alloc((size_t)SCAN_NB * 4);
    float*          We3      = (float*)alloc(3 * 64 * 4 * 4);
    int*            bstart   = (int*)  alloc((NB + 1) * 4);
    float*          psum     = (float*)alloc((size_t)NB * PARTS * HID * 4);
    float*          pmax     = (float*)alloc((size_t)NB * PARTS * HID * 4);

    // encoder
    hipLaunchKernelGGL(enc_kernel, dim3(N_NODES), dim3(128), 0, stream,
                       x, enc_w, enc_b, enc_g, enc_beta, h);

    // CSR build: rank (single pass) + scan (writes self entries) + atomic-free scatter
    hipMemsetAsync(row_count, 0, (size_t)N_NODES * 4, stream);
    hipLaunchKernelGGL(rank_kernel, dim3((N_EDGES + 255) / 256), dim3(256), 0, stream,
                       edge_idx, row_count, rank);
    hipLaunchKernelGGL(scan1_kernel, dim3(SCAN_NB), dim3(256), 0, stream, row_count, bsum);
    hipLaunchKernelGGL(scan2_kernel, dim3(1), dim3(256), 0, stream, bsum);
    hipLaunchKernelGGL(scan3_kernel, dim3(SCAN_NB), dim3(256), 0, stream,
                       row_count, bsum, row_ptr, csr_se, alp0, alp1, alp2);
    {
        int slices_s = (N_EDGES + SEPB - 1) / SEPB;
        hipLaunchKernelGGL(scatter_kernel, dim3(slices_s * NPART4), dim3(256), 0, stream,
                           edge_idx, rank, row_ptr, csr_se);
    }

    // all-layer edge attention terms, CSR-position order (coalesced writes + reads in agg)
    hipLaunchKernelGGL(we3_kernel, dim3(1), dim3(256), 0, stream, gat_edge_w, att_edge, We3);
    hipLaunchKernelGGL(ae_pos_kernel, dim3((TOT + 255) / 256), dim3(256), 0, stream,
                       (const int2*)csr_se, (const float4*)edge_attr, ee_w, ee_b, We3,
                       alp0, alp1, alp2);
    hipLaunchKernelGGL(selfae_kernel, dim3(N_NODES), dim3(64), 0, stream,
                       row_ptr, alp0, alp1, alp2);

    // GAT layers
    uint2* alps[3] = {alp0, alp1, alp2};
    int gemm_blocks = (N_NODES + GM_ROWS - 1) / GM_ROWS;
    for (int l = 0; l < 3; l++){
        hipLaunchKernelGGL(gemm_hh_kernel, dim3(gemm_blocks), dim3(256), 0, stream,
                           h, gat_lin_w + (size_t)l * HID * HID,
                           att_src + (size_t)l * HID, att_dst + (size_t)l * HID,
                           hh8, a_s, a_d);
        hipLaunchKernelGGL(agg_kernel, dim3(N_NODES), dim3(64), 0, stream,
                           a_s, a_d, row_ptr, (const int2*)csr_se,
                           (const uint2*)alps[l], (const uint2*)hh8, h,
                           gat_bias + (size_t)l * HID, norm_g + (size_t)l * HID,
                           norm_b + (size_t)l * HID);
    }

    // pooling + MLP
    hipLaunchKernelGGL(bounds_kernel, dim3(1), dim3(128), 0, stream, batch, bstart);
    hipLaunchKernelGGL(pool_kernel, dim3(NB, PARTS), dim3(128), 0, stream, h, bstart, psum, pmax);
    hipLaunchKernelGGL(mlp_kernel, dim3(NB), dim3(128), 0, stream,
                       psum, pmax, bstart, fw1, fb1, fw2, fb2, cw1, cb1, cw2, cb2, out);
}